// Round 1
// baseline (204.107 us; speedup 1.0000x reference)
//
#include <hip/hip_runtime.h>
#include <hip/hip_bf16.h>

#define PREFIX_N 20000
#define LEAF_N   50000
#define NONLEAF_N 50000
#define CH_N     (LEAF_N + NONLEAF_N)   /* 100000 */
#define CCOL     256
#define GK       2048
#define GM       NONLEAF_N              /* 50000 */
#define OUT_ROWS (PREFIX_N + CH_N)      /* 120000 */
#define NKT      (GK / 32)              /* 64 K-steps */

typedef float  f32x4v __attribute__((ext_vector_type(4)));
typedef __bf16 bf16x8 __attribute__((ext_vector_type(8)));
typedef short  s16x8  __attribute__((ext_vector_type(8)));

static __device__ __forceinline__ unsigned pk2(float a, float b) {
  __hip_bfloat16 ha = __float2bfloat16(a);
  __hip_bfloat16 hb = __float2bfloat16(b);
  unsigned short sa = __builtin_bit_cast(unsigned short, ha);
  unsigned short sb = __builtin_bit_cast(unsigned short, hb);
  return (unsigned)sa | ((unsigned)sb << 16);
}
static __device__ __forceinline__ uint4 pack8(const float4& x, const float4& y) {
  uint4 r;
  r.x = pk2(x.x, x.y); r.y = pk2(x.z, x.w);
  r.z = pk2(y.x, y.y); r.w = pk2(y.z, y.w);
  return r;
}

// ---- rank pipeline -------------------------------------------------------
__global__ __launch_bounds__(256) void count_leaves(const int* __restrict__ ch,
                                                    int n, int* __restrict__ cnt) {
  int gi = blockIdx.x * 256 + threadIdx.x;
  int lm = (gi < n && ch[gi] < 0) ? 1 : 0;
  unsigned long long mask = __ballot(lm);
  __shared__ int wsum[4];
  int lane = threadIdx.x & 63, w = threadIdx.x >> 6;
  if (lane == 0) wsum[w] = __popcll(mask);
  __syncthreads();
  if (threadIdx.x == 0) cnt[blockIdx.x] = wsum[0] + wsum[1] + wsum[2] + wsum[3];
}

__global__ __launch_bounds__(512) void scan_blocks(const int* __restrict__ cnt,
                                                   int* __restrict__ boff, int nb) {
  __shared__ int s[512];
  int t = threadIdx.x;
  int v = (t < nb) ? cnt[t] : 0;
  s[t] = v;
  __syncthreads();
  for (int d = 1; d < 512; d <<= 1) {
    int add = (t >= d) ? s[t - d] : 0;
    __syncthreads();
    s[t] += add;
    __syncthreads();
  }
  if (t < nb) boff[t] = s[t] - v;   // exclusive scan of leaf counts
}

__global__ __launch_bounds__(256) void rank_kernel(const int* __restrict__ ch,
                                                   const int* __restrict__ boff, int n,
                                                   int* __restrict__ idx,
                                                   int* __restrict__ rowof) {
  int gi = blockIdx.x * 256 + threadIdx.x;
  int lane = threadIdx.x & 63, w = threadIdx.x >> 6;
  int lm = (gi < n && ch[gi] < 0) ? 1 : 0;
  unsigned long long mask = __ballot(lm);
  int lrank = __popcll(mask & ((1ull << lane) - 1ull));
  __shared__ int wcnt[4];
  if (lane == 63) wcnt[w] = lrank + lm;
  __syncthreads();
  int woff = 0;
  for (int i = 0; i < w; ++i) woff += wcnt[i];
  if (gi < n) {
    int rl = boff[blockIdx.x] + woff + lrank;   // leaves strictly before gi
    if (lm) {
      idx[gi] = rl;
    } else {
      int rn = gi - rl;                          // nonleaves strictly before gi
      idx[gi] = LEAF_N + rn;
      rowof[rn] = gi;                            // inverse map for GEMM scatter
    }
  }
}

// ---- prefix + leaf copies ------------------------------------------------
__global__ __launch_bounds__(256) void copy_rows(const float* __restrict__ x,
                                                 const int* __restrict__ idx,
                                                 float* __restrict__ out) {
  int row = blockIdx.x * 4 + (threadIdx.x >> 6);
  if (row >= OUT_ROWS) return;
  int lane = threadIdx.x & 63;
  const float* src;
  if (row < PREFIX_N) {
    src = x + (size_t)row * CCOL;
  } else {
    int id = idx[row - PREFIX_N];
    if (id >= LEAF_N) return;                    // nonleaf: GEMM writes it
    src = x + (size_t)(PREFIX_N + id) * CCOL;
  }
  float4 v = ((const float4*)src)[lane];
  ((float4*)(out + (size_t)row * CCOL))[lane] = v;
}

// ---- GEMM: out[PREFIX+rowof[m]] = A[m,:] @ W^T ---------------------------
// BM=128 BN=256 BK=32, 512 threads = 8 waves (2m x 4n), wave tile 64x64.
__global__ __launch_bounds__(512, 2) void gemm_kernel(const float* __restrict__ A,
                                                      const float* __restrict__ W,
                                                      const int* __restrict__ rowof,
                                                      float* __restrict__ out) {
  __shared__ unsigned short Alds[128][40];   // +8 pad: 80B stride, 2-way banks (free)
  __shared__ unsigned short Blds[256][40];
  __shared__ int tgt[128];

  const int tid  = threadIdx.x;
  const int lane = tid & 63;
  const int w    = tid >> 6;
  const int wm   = w >> 2;          // 0..1
  const int wn   = w & 3;           // 0..3
  const int tile_m = blockIdx.x;

  // scatter targets for this block's 128 rows
  if (tid < 128) {
    int m = tile_m * 128 + tid;
    tgt[tid] = (m < GM) ? (PREFIX_N + rowof[m]) : -1;
  }

  // staging assignment: A 128x32 (8 f/thread), B 256x32 (16 f/thread)
  const int ar = tid >> 2;          // 0..127
  const int ac = (tid & 3) * 8;     // 0,8,16,24
  const int br = tid >> 1;          // 0..255
  const int bc = (tid & 1) * 16;    // 0,16

  int agr = tile_m * 128 + ar;
  if (agr >= GM) agr = GM - 1;      // clamp tail loads (stores predicated)
  const float* aptr = A + (size_t)agr * GK + ac;
  const float* bptr = W + (size_t)br  * GK + bc;

  f32x4v acc[4][4] = {};

  // prologue: load K-tile 0
  float4 fa0, fa1, fb0, fb1, fb2, fb3;
  fa0 = ((const float4*)aptr)[0]; fa1 = ((const float4*)aptr)[1];
  fb0 = ((const float4*)bptr)[0]; fb1 = ((const float4*)bptr)[1];
  fb2 = ((const float4*)bptr)[2]; fb3 = ((const float4*)bptr)[3];
  uint4 aS  = pack8(fa0, fa1);
  uint4 bS0 = pack8(fb0, fb1);
  uint4 bS1 = pack8(fb2, fb3);

  const int lr = lane & 15, lq = lane >> 4;

  for (int kt = 0; kt < NKT; ++kt) {
    __syncthreads();                               // prev reads done
    *(uint4*)&Alds[ar][ac]     = aS;
    *(uint4*)&Blds[br][bc]     = bS0;
    *(uint4*)&Blds[br][bc + 8] = bS1;
    __syncthreads();                               // tile kt visible

    if (kt + 1 < NKT) {                            // issue next loads; drain lands
      const float* ap = aptr + (kt + 1) * 32;      // after MFMA at next barrier
      fa0 = ((const float4*)ap)[0]; fa1 = ((const float4*)ap)[1];
      const float* bp = bptr + (kt + 1) * 32;
      fb0 = ((const float4*)bp)[0]; fb1 = ((const float4*)bp)[1];
      fb2 = ((const float4*)bp)[2]; fb3 = ((const float4*)bp)[3];
    }

    s16x8 af[4], bf[4];
#pragma unroll
    for (int fm = 0; fm < 4; ++fm)
      af[fm] = *(const s16x8*)&Alds[wm * 64 + fm * 16 + lr][lq * 8];
#pragma unroll
    for (int fn = 0; fn < 4; ++fn)
      bf[fn] = *(const s16x8*)&Blds[wn * 64 + fn * 16 + lr][lq * 8];
#pragma unroll
    for (int fm = 0; fm < 4; ++fm)
#pragma unroll
      for (int fn = 0; fn < 4; ++fn)
        acc[fm][fn] = __builtin_amdgcn_mfma_f32_16x16x32_bf16(
            __builtin_bit_cast(bf16x8, af[fm]),
            __builtin_bit_cast(bf16x8, bf[fn]),
            acc[fm][fn], 0, 0, 0);

    if (kt + 1 < NKT) {
      aS  = pack8(fa0, fa1);
      bS0 = pack8(fb0, fb1);
      bS1 = pack8(fb2, fb3);
    }
  }

  // epilogue: scatter rows to final output positions
#pragma unroll
  for (int fm = 0; fm < 4; ++fm) {
    int mlb = wm * 64 + fm * 16 + lq * 4;
    int t0 = tgt[mlb + 0], t1 = tgt[mlb + 1], t2 = tgt[mlb + 2], t3 = tgt[mlb + 3];
#pragma unroll
    for (int fn = 0; fn < 4; ++fn) {
      int col = wn * 64 + fn * 16 + lr;
      if (t0 >= 0) out[(size_t)t0 * CCOL + col] = acc[fm][fn][0];
      if (t1 >= 0) out[(size_t)t1 * CCOL + col] = acc[fm][fn][1];
      if (t2 >= 0) out[(size_t)t2 * CCOL + col] = acc[fm][fn][2];
      if (t3 >= 0) out[(size_t)t3 * CCOL + col] = acc[fm][fn][3];
    }
  }
}

extern "C" void kernel_launch(void* const* d_in, const int* in_sizes, int n_in,
                              void* d_out, int out_size, void* d_ws, size_t ws_size,
                              hipStream_t stream) {
  const float* x        = (const float*)d_in[0];
  const float* wts      = (const float*)d_in[1];   // (256,256,8) == row-major (256,2048)
  const int*   children = (const int*)d_in[2];
  float*       out      = (float*)d_out;

  int* wsp   = (int*)d_ws;
  int* cnt   = wsp;              // 391
  int* boff  = wsp + 512;        // 391
  int* idx   = wsp + 1024;       // 100000
  int* rowof = wsp + 1024 + CH_N;// 50000   (total ~604 KB of ws)

  const int nb = (CH_N + 255) / 256;   // 391

  count_leaves<<<nb, 256, 0, stream>>>(children, CH_N, cnt);
  scan_blocks<<<1, 512, 0, stream>>>(cnt, boff, nb);
  rank_kernel<<<nb, 256, 0, stream>>>(children, boff, CH_N, idx, rowof);

  copy_rows<<<(OUT_ROWS + 3) / 4, 256, 0, stream>>>(x, idx, out);

  const float* A = x + (size_t)(PREFIX_N + LEAF_N) * CCOL;
  gemm_kernel<<<(GM + 127) / 128, 512, 0, stream>>>(A, wts, rowof, out);
}